// Round 6
// baseline (938.150 us; speedup 1.0000x reference)
//
#include <hip/hip_runtime.h>

#define B_ 16
#define C_ 64
#define H_ 128
#define W_ 256
#define K_ 9
#define KDIM_ (K_*C_)            // 576

typedef __attribute__((ext_vector_type(8))) short short8_t;
typedef __attribute__((ext_vector_type(4))) float f32x4;

static __device__ __forceinline__ float bf2f(unsigned short u) {
  union { unsigned int i; float f; } v; v.i = ((unsigned int)u) << 16; return v.f;
}
static __device__ __forceinline__ unsigned short f2bf(float f) {
  union { float f; unsigned int i; } v; v.f = f;
  unsigned int r = v.i + 0x7FFF + ((v.i >> 16) & 1);   // RNE
  return (unsigned short)(r >> 16);
}

// async global->LDS, 16B per lane; lds ptr wave-uniform, lanes fill +lane*16
static __device__ __forceinline__ void gload_lds16(const void* g, void* l) {
  __builtin_amdgcn_global_load_lds(
      (const __attribute__((address_space(1))) unsigned int*)g,
      (__attribute__((address_space(3))) unsigned int*)l, 16, 0, 0);
}

// All 4 weight tensors [co][ci][kk] fp32 -> A2 chunk layout (16B chunk = 8
// consecutive k for one co): A2[(c*64+co)*8 + (k&7)], c = k>>3, k = kk*64+ci.
__global__ __launch_bounds__(256) void prep_w_all(const float* __restrict__ w0,
                                                  const float* __restrict__ w1,
                                                  const float* __restrict__ w2,
                                                  const float* __restrict__ w3,
                                                  unsigned short* __restrict__ A2) {
  int idx = blockIdx.x * 256 + threadIdx.x;
  if (idx >= C_ * KDIM_) return;
  int which = blockIdx.y;
  const float* w = (which == 0) ? w0 : (which == 1) ? w1 : (which == 2) ? w2 : w3;
  unsigned short* out = A2 + (size_t)which * (C_ * KDIM_);
  int co = idx / KDIM_, k = idx % KDIM_;
  int ci = k & 63, kk = k >> 6;
  out[((size_t)(k >> 3) * 64 + co) * 8 + (k & 7)] =
      f2bf(w[((size_t)co * C_ + ci) * K_ + kk]);
}

// fp32 NCHW -> bf16 ci-minor [b][h][w][ci]
__global__ __launch_bounds__(256) void transpose_in(const float* __restrict__ x,
                                                    unsigned short* __restrict__ Xt) {
  __shared__ float tile[64][65];
  const int w0 = blockIdx.x * 64, h = blockIdx.y, b = blockIdx.z;
  const int t = threadIdx.x;
#pragma unroll
  for (int rep = 0; rep < 16; ++rep) {
    int idx = rep * 256 + t;
    int ci = idx >> 6, wl = idx & 63;
    tile[ci][wl] = x[((size_t)(b * C_ + ci) * H_ + h) * W_ + w0 + wl];
  }
  __syncthreads();
#pragma unroll
  for (int rep = 0; rep < 8; ++rep) {
    int idx = rep * 256 + t;
    int wl = idx >> 5, cp = idx & 31;
    unsigned v = (unsigned)f2bf(tile[cp*2][wl]) | ((unsigned)f2bf(tile[cp*2+1][wl]) << 16);
    *(unsigned*)(Xt + ((size_t)(b * H_ + h) * W_ + w0 + wl) * C_ + cp * 2) = v;
  }
}

// bf16 ci-minor -> fp32 NCHW (final output)
__global__ __launch_bounds__(256) void transpose_out(const unsigned short* __restrict__ F,
                                                     float* __restrict__ out) {
  __shared__ float tile[64][65];
  const int w0 = blockIdx.x * 64, h = blockIdx.y, b = blockIdx.z;
  const int t = threadIdx.x;
#pragma unroll
  for (int rep = 0; rep < 8; ++rep) {
    int idx = rep * 256 + t;
    int wl = idx >> 5, cp = idx & 31;
    unsigned v = *(const unsigned*)(F + ((size_t)(b * H_ + h) * W_ + w0 + wl) * C_ + cp * 2);
    tile[cp*2][wl]   = bf2f((unsigned short)v);
    tile[cp*2+1][wl] = bf2f((unsigned short)(v >> 16));
  }
  __syncthreads();
#pragma unroll
  for (int rep = 0; rep < 16; ++rep) {
    int idx = rep * 256 + t;
    int ci = idx >> 6, wl = idx & 63;
    out[((size_t)(b * C_ + ci) * H_ + h) * W_ + w0 + wl] = tile[ci][wl];
  }
}

// ===== Single-wave fused conv+scan =====
// MODE 0: staged axis w (tile 16 +-4 pad), iterate h (scan axis), grid (16,16).
// MODE 1: staged axis h, iterate w, grid (8,16).
// One wave (64 thr) per block. All 72 weight fragments in registers (288 VGPR).
// Per position-pair: stage next pair via global_load_lds (ring of 4 x 6KB slots,
// chunk-XOR swizzle via pre-swizzled source), counted vmcnt(40) (in-order VMEM
// retirement: 42 ops issued after the needed pair's loads -> <=40 outstanding
// implies pair landed). NO barriers. 8 interleaved MFMA chains (2 pos x 4 tiles).
template<int MODE, int REV>
__global__ __launch_bounds__(64, 1) void fused1w(const unsigned short* __restrict__ X,
                                                 unsigned short* __restrict__ Y,
                                                 const unsigned short* __restrict__ A2,
                                                 const float* __restrict__ bias,
                                                 const unsigned short* __restrict__ ZP) {
  __shared__ __align__(16) char lds[4 * 6144];
  const int lane = threadIdx.x;
  const int llo = lane & 15, lhi = lane >> 4;
  const int b = blockIdx.y;
  const int s0 = blockIdx.x * 16;
  constexpr int NPOS  = MODE ? W_ : H_;
  constexpr int NPAIR = NPOS / 2;
  constexpr int SLEN  = MODE ? H_ : W_;   // staged-axis length (bounds check)

  // ---- all weight fragments -> registers (72 x 16B per lane) ----
  short8_t areg[18][4];
#pragma unroll
  for (int st = 0; st < 18; ++st)
#pragma unroll
    for (int j = 0; j < 4; ++j)
      areg[st][j] = *(const short8_t*)(A2 + (size_t)((st*4 + lhi)*64 + j*16 + llo) * 8);
  float4 bv[4];
#pragma unroll
  for (int j = 0; j < 4; ++j) bv[j] = *(const float4*)(bias + j*16 + lhi*4);

  auto stagePair = [&](int k) {
#pragma unroll
    for (int sub = 0; sub < 2; ++sub) {
      int i = 2*k + sub;
      int p = REV ? (NPOS - 1 - i) : i;
      char* dst = lds + (k & 3)*6144 + sub*3072;
#pragma unroll
      for (int g = 0; g < 3; ++g) {
        int r = g*8 + (lane >> 3);          // staged-row 0..23
        int chunk = (lane & 7) ^ (r & 7);   // pre-swizzled source chunk
        int sp_ = s0 - 4 + r;
        const void* src;
        if ((unsigned)sp_ < (unsigned)SLEN) {
          size_t goff = MODE ? (((size_t)(b*H_ + sp_)*W_ + p)*C_ + chunk*8)
                             : (((size_t)(b*H_ + p)*W_ + sp_)*C_ + chunk*8);
          src = (const void*)(X + goff);
        } else {
          src = (const void*)((const char*)ZP + (lane & 7)*16);
        }
        gload_lds16(src, dst + g*1024);
      }
    }
  };

  auto outOff = [&](int p, int j) -> size_t {
    return MODE ? (((size_t)(b*H_ + s0 + llo)*W_ + p)*C_ + j*16 + lhi*4)
                : (((size_t)(b*H_ + p)*W_ + s0 + llo)*C_ + j*16 + lhi*4);
  };

  float y[16];

  auto relustore = [&](f32x4 acc[4], int p) {
#pragma unroll
    for (int j = 0; j < 4; ++j) {
      y[j*4+0] = fmaxf(acc[j][0] + bv[j].x + y[j*4+0], 0.f);
      y[j*4+1] = fmaxf(acc[j][1] + bv[j].y + y[j*4+1], 0.f);
      y[j*4+2] = fmaxf(acc[j][2] + bv[j].z + y[j*4+2], 0.f);
      y[j*4+3] = fmaxf(acc[j][3] + bv[j].w + y[j*4+3], 0.f);
      unsigned lo, hi;
      asm("v_cvt_pk_bf16_f32 %0, %1, %2" : "=v"(lo) : "v"(y[j*4+0]), "v"(y[j*4+1]));
      asm("v_cvt_pk_bf16_f32 %0, %1, %2" : "=v"(hi) : "v"(y[j*4+2]), "v"(y[j*4+3]));
      uint2 ov; ov.x = lo; ov.y = hi;
      *(uint2*)(Y + outOff(p, j)) = ov;
    }
  };

  // ---- prologue: stage pairs 0..2, drain everything once ----
  stagePair(0); stagePair(1); stagePair(2);
  asm volatile("s_waitcnt vmcnt(0)" ::: "memory");

  // ---- peeled pair 0: passthrough pos0 + conv pos1 ----
  {
    stagePair(3);
    const int p0 = REV ? NPOS - 1 : 0;
    const int row0 = llo + 4;
#pragma unroll
    for (int j = 0; j < 4; ++j) {
      int cj = 2*j + (lhi >> 1);
      uint2 v = *(const uint2*)(lds + row0*128 + ((cj ^ (row0 & 7)) << 4) + (lhi & 1)*8);
      y[j*4+0] = bf2f((unsigned short)v.x);
      y[j*4+1] = bf2f((unsigned short)(v.x >> 16));
      y[j*4+2] = bf2f((unsigned short)v.y);
      y[j*4+3] = bf2f((unsigned short)(v.y >> 16));
      *(uint2*)(Y + outOff(p0, j)) = v;    // boundary row copied bit-exact
    }
    const int p1 = REV ? NPOS - 2 : 1;
    f32x4 acc[4];
#pragma unroll
    for (int j = 0; j < 4; ++j) { f32x4 z = {0.f,0.f,0.f,0.f}; acc[j] = z; }
#pragma unroll
    for (int st = 0; st < 18; ++st) {
      int row = llo + (st >> 1);
      int cg  = (st & 1)*4 + lhi;
      short8_t f = *(const short8_t*)(lds + 3072 + row*128 + ((cg ^ (row & 7)) << 4));
#pragma unroll
      for (int j = 0; j < 4; ++j)
        acc[j] = __builtin_amdgcn_mfma_f32_16x16x32_bf16(areg[st][j], f, acc[j], 0, 0, 0);
    }
    relustore(acc, p1);
  }

  // ---- main loop: 2 positions per iteration ----
  for (int i = 1; i < NPAIR; ++i) {
    if (i + 3 < NPAIR) stagePair(i + 3);
    asm volatile("s_waitcnt vmcnt(40)" ::: "memory");
    const char* spA = lds + (i & 3)*6144;
    f32x4 accA[4], accB[4];
#pragma unroll
    for (int j = 0; j < 4; ++j) { f32x4 z = {0.f,0.f,0.f,0.f}; accA[j] = z; accB[j] = z; }
#pragma unroll
    for (int st = 0; st < 18; ++st) {
      int row = llo + (st >> 1);
      int so  = row*128 + ((((st & 1)*4 + lhi) ^ (row & 7)) << 4);
      short8_t fA = *(const short8_t*)(spA + so);
      short8_t fB = *(const short8_t*)(spA + 3072 + so);
#pragma unroll
      for (int j = 0; j < 4; ++j)
        accA[j] = __builtin_amdgcn_mfma_f32_16x16x32_bf16(areg[st][j], fA, accA[j], 0, 0, 0);
#pragma unroll
      for (int j = 0; j < 4; ++j)
        accB[j] = __builtin_amdgcn_mfma_f32_16x16x32_bf16(areg[st][j], fB, accB[j], 0, 0, 0);
    }
    const int pA = REV ? (NPOS - 1 - 2*i) : 2*i;
    const int pB = REV ? (pA - 1) : (pA + 1);
    relustore(accA, pA);
    relustore(accB, pB);
  }
}

extern "C" void kernel_launch(void* const* d_in, const int* in_sizes, int n_in,
                              void* d_out, int out_size, void* d_ws, size_t ws_size,
                              hipStream_t stream) {
  const float* x    = (const float*)d_in[0];
  const float* w_ud = (const float*)d_in[1];
  const float* b_ud = (const float*)d_in[2];
  const float* w_du = (const float*)d_in[3];
  const float* b_du = (const float*)d_in[4];
  const float* w_lr = (const float*)d_in[5];
  const float* b_lr = (const float*)d_in[6];
  const float* w_rl = (const float*)d_in[7];
  const float* b_rl = (const float*)d_in[8];

  // ws: A[0,64M) Bb[64M,128M) Cc[128M,192M) A2 @192M, zeropage @192M+1M
  unsigned short* A  = (unsigned short*)d_ws;
  unsigned short* Bb = (unsigned short*)((char*)d_ws + 67108864);
  unsigned short* Cc = (unsigned short*)((char*)d_ws + 134217728);
  unsigned short* A2 = (unsigned short*)((char*)d_ws + 201326592);
  unsigned short* ZP = (unsigned short*)((char*)d_ws + 202375168);
  unsigned short* A2_ud = A2 + 0 * (C_ * KDIM_);
  unsigned short* A2_du = A2 + 1 * (C_ * KDIM_);
  unsigned short* A2_lr = A2 + 2 * (C_ * KDIM_);
  unsigned short* A2_rl = A2 + 3 * (C_ * KDIM_);

  hipMemsetAsync(ZP, 0, 1024, stream);

  dim3 pg((C_ * KDIM_ + 255) / 256, 4);
  prep_w_all<<<pg, 256, 0, stream>>>(w_ud, w_du, w_lr, w_rl, A2);

  transpose_in<<<dim3(4, H_, B_), 256, 0, stream>>>(x, A);

  // sweep 1: conv along W, scan along H (fwd)
  fused1w<0,0><<<dim3(16, B_), 64, 0, stream>>>(A,  Bb, A2_ud, b_ud, ZP);
  // sweep 2: conv along W, scan along H (rev)
  fused1w<0,1><<<dim3(16, B_), 64, 0, stream>>>(Bb, Cc, A2_du, b_du, ZP);
  // sweep 3: conv along H, scan along W (fwd)
  fused1w<1,0><<<dim3(8, B_), 64, 0, stream>>>(Cc, A, A2_lr, b_lr, ZP);
  // sweep 4: conv along H, scan along W (rev)
  fused1w<1,1><<<dim3(8, B_), 64, 0, stream>>>(A, Bb, A2_rl, b_rl, ZP);

  transpose_out<<<dim3(4, H_, B_), 256, 0, stream>>>(Bb, (float*)d_out);
}